// Round 14
// baseline (171.258 us; speedup 1.0000x reference)
//
#include <hip/hip_runtime.h>
#include <cmath>

#define TABLE_SZ 16384
#define NLEV 16
#define BLOCK 512
#define NLDS 11        // levels 0..10: LDS bf16 pipeline; 11..15: global f32 (TA pipe)

struct ResArr { float r[NLEV]; };

// ---------------- prologue: tables f32 -> packed bf16x2 (RNE) ---------------
__global__ __launch_bounds__(256) void cvt_tables(
    const float* __restrict__ src, uint32_t* __restrict__ dst, int n_entries)
{
    int i = blockIdx.x * blockDim.x + threadIdx.x;
    int e = i * 4;
    if (e + 3 < n_entries) {
        const float4* s4 = (const float4*)(src) + i * 2;
        float4 a = s4[0], b = s4[1];
        uint32_t o[4];
        float v[8] = {a.x,a.y,a.z,a.w,b.x,b.y,b.z,b.w};
        #pragma unroll
        for (int k = 0; k < 4; ++k) {
            uint32_t lo = __float_as_uint(v[2*k+0]);
            uint32_t hi = __float_as_uint(v[2*k+1]);
            lo = (lo + 0x7FFFu + ((lo >> 16) & 1u)) >> 16;     // RNE to bf16
            hi = (hi + 0x7FFFu + ((hi >> 16) & 1u)) & 0xFFFF0000u;
            o[k] = lo | hi;
        }
        *(uint4*)(dst + e) = make_uint4(o[0], o[1], o[2], o[3]);
    }
}

// ---------------- helpers ----------------------------------------------------
template <int TBLOCK>
__device__ __forceinline__ void stage_bf(const uint32_t* __restrict__ tb, int l,
                                         uint32_t* buf, int tid, int wid)
{
    const char* gbase = (const char*)tb + (size_t)l * (TABLE_SZ * 4);
    #pragma unroll
    for (int j = 0; j < (TABLE_SZ * 4) / (TBLOCK * 16); ++j) {
        uint32_t goff = (uint32_t)(j * (TBLOCK * 16) + tid * 16);   // per-lane
        uint32_t loff = (uint32_t)(j * (TBLOCK * 16) + wid * 1024); // wave-uniform
        __builtin_amdgcn_global_load_lds(
            (const __attribute__((address_space(1))) uint32_t*)(gbase + goff),
            (__attribute__((address_space(3))) uint32_t*)((char*)buf + loff),
            16, 0, 0);
    }
}

// 8 corner hash indices for (px,py,pz) at resolution r.
// high = ceil (NOT low+1); low = trunc (sp in [0,512) >= 0).
struct C8 { uint32_t h[8]; };
__device__ __forceinline__ C8 corner_idx(float r, float px, float py, float pz)
{
    const uint32_t P1 = 2654435761u, P2 = 805459861u;
    const uint32_t m  = TABLE_SZ - 1u;
    float sx = r*px, sy = r*py, sz = r*pz;
    uint32_t lx = (uint32_t)sx,  hx = (uint32_t)ceilf(sx);
    uint32_t ly = (uint32_t)sy,  hy = (uint32_t)ceilf(sy);
    uint32_t lz = (uint32_t)sz,  hz = (uint32_t)ceilf(sz);
    uint32_t yl = P1*ly, yh = P1*hy, zl = P2*lz, zh = P2*hz;
    C8 c;
    c.h[0] = (lx ^ yl ^ zl) & m;
    c.h[1] = (hx ^ yl ^ zl) & m;
    c.h[2] = (hx ^ yh ^ zl) & m;
    c.h[3] = (lx ^ yh ^ zl) & m;
    c.h[4] = (lx ^ yl ^ zh) & m;
    c.h[5] = (hx ^ yl ^ zh) & m;
    c.h[6] = (hx ^ yh ^ zh) & m;
    c.h[7] = (lx ^ yh ^ zh) & m;
    return c;
}

// x in [0,1): interp weight w = x - floor(x) == x exactly (faithful).
// cw precomputed per point: product order (x*y)*z, corners v0..v7,
// k-ascending accumulation.
__device__ __forceinline__ float2 level_accum_bf(const uint32_t* tab, float r,
                                                 float px, float py, float pz,
                                                 const float* cw)
{
    C8 c = corner_idx(r, px, py, pz);
    float a0 = 0.f, a1 = 0.f;
    #pragma unroll
    for (int k = 0; k < 8; ++k) {
        uint32_t v = tab[c.h[k]];
        a0 += __uint_as_float(v << 16)         * cw[k];
        a1 += __uint_as_float(v & 0xFFFF0000u) * cw[k];
    }
    return make_float2(a0, a1);
}

// -------- hybrid kernel: LDS pipe (levels 0..10) + TA pipe (levels 11..15) ---
// Per iter l: stage l+1 (8 loads) -> vmcnt(8) waits PRIOR stage (counted,
// in-order) -> barrier -> [iters 5..9: issue 8 global float2 gathers for level
// l+6] -> LDS gather level l -> [consume globals; compiler auto-waitcnt
// protects register consumers] -> window writes -> barrier (buf reuse).
__global__ __launch_bounds__(BLOCK) void mrhe_hyb(
    const float* __restrict__ x,
    const float* __restrict__ ftab,   // original f32 tables (levels 11..15)
    const uint32_t* __restrict__ tb,  // packed bf16x2 tables (levels 0..10)
    float* __restrict__ out,
    ResArr res, int B)
{
    __shared__ uint32_t tab[2][TABLE_SZ];   // 2 x 64 KiB

    const int tid = threadIdx.x;
    const int wid = tid >> 6;
    const int idx = blockIdx.x * BLOCK + tid;
    const size_t j = (idx < B) ? (size_t)idx : 0;

    const float px = x[3*j+0], py = x[3*j+1], pz = x[3*j+2];
    const float ax = 1.0f - px, ay = 1.0f - py, az = 1.0f - pz;
    float cw[8];
    cw[0] = (ax*ay)*az;  cw[1] = (px*ay)*az;
    cw[2] = (px*py)*az;  cw[3] = (ax*py)*az;
    cw[4] = (ax*ay)*pz;  cw[5] = (px*ay)*pz;
    cw[6] = (px*py)*pz;  cw[7] = (ax*py)*pz;

    stage_bf<BLOCK>(tb, 0, tab[0], tid, wid);   // prologue: level 0 -> buf 0

    float o[16];      // current 64B window (8 levels x 2 feats)
    float opre[6];    // parking for global levels 11,12,13 (consumed pre-flush)

    #pragma unroll
    for (int l = 0; l < NLDS; ++l) {
        if (l + 1 < NLDS) {
            stage_bf<BLOCK>(tb, l + 1, tab[(l + 1) & 1], tid, wid);
            asm volatile("s_waitcnt vmcnt(8)" ::: "memory");   // prior stage done
        } else {
            asm volatile("s_waitcnt vmcnt(0)" ::: "memory");
        }
        asm volatile("s_barrier" ::: "memory");   // level-l DMA visible to all

        // ---- TA pipe: issue global gathers for level g = l+6 (11..15) ----
        float2 gf[8];
        if (l >= 5 && l <= 9) {
            const int g = l + 6;
            C8 c = corner_idx(res.r[g], px, py, pz);
            const float2* t = (const float2*)ftab + (size_t)g * TABLE_SZ;
            #pragma unroll
            for (int k = 0; k < 8; ++k) gf[k] = t[c.h[k]];
        }

        // ---- DS pipe: LDS gather for level l (hides globals' L2 latency) ----
        {
            float2 a = level_accum_bf(tab[l & 1], res.r[l], px, py, pz, cw);
            o[2*(l & 7) + 0] = a.x;
            o[2*(l & 7) + 1] = a.y;
        }

        // ---- consume globals (compiler inserts the protecting waitcnt) ----
        if (l >= 5 && l <= 9) {
            const int g = l + 6;
            float b0 = 0.f, b1 = 0.f;
            #pragma unroll
            for (int k = 0; k < 8; ++k) {
                b0 += gf[k].x * cw[k];
                b1 += gf[k].y * cw[k];
            }
            if (l <= 7) {               // g=11,12,13: window0 still live -> park
                opre[2*(l-5) + 0] = b0;
                opre[2*(l-5) + 1] = b1;
            } else {                    // g=14,15: direct into window1 slots
                o[2*(g & 7) + 0] = b0;
                o[2*(g & 7) + 1] = b1;
            }
        }

        if (l == 7 && idx < B) {        // flush window0: levels 0..7 (64 B)
            float4* po = (float4*)(out + (size_t)idx * (2*NLEV));
            #pragma unroll
            for (int q = 0; q < 4; ++q) {
                float4 v;
                v.x = o[4*q+0]; v.y = o[4*q+1]; v.z = o[4*q+2]; v.w = o[4*q+3];
                po[q] = v;
            }
        }
        if (l == 8) {                   // unpark g11,g12,g13 -> window1 slots
            o[6]  = opre[0]; o[7]  = opre[1];
            o[8]  = opre[2]; o[9]  = opre[3];
            o[10] = opre[4]; o[11] = opre[5];
        }
        if (l == 10 && idx < B) {       // flush window1: levels 8..15 (64 B)
            float4* po = (float4*)(out + (size_t)idx * (2*NLEV) + 16);
            #pragma unroll
            for (int q = 0; q < 4; ++q) {
                float4 v;
                v.x = o[4*q+0]; v.y = o[4*q+1]; v.z = o[4*q+2]; v.w = o[4*q+3];
                po[q] = v;
            }
        }

        asm volatile("s_barrier" ::: "memory");   // protect buf before reuse
    }
}

// -------- fallback: r12's proven pure-LDS kernel (108 us) -------------------
template <int TBLOCK, int TPPT>
__global__ __launch_bounds__(TBLOCK) void mrhe_db(
    const float* __restrict__ x,
    const uint32_t* __restrict__ tb,
    float* __restrict__ out,
    ResArr res, int B)
{
    constexpr int ROUNDS = (TABLE_SZ * 4) / (TBLOCK * 16);
    static_assert(ROUNDS == 8, "vmcnt literal must match");

    __shared__ uint32_t tab[2][TABLE_SZ];

    const int tid  = threadIdx.x;
    const int wid  = tid >> 6;
    const int base = blockIdx.x * (TBLOCK * TPPT);

    float px[TPPT], py[TPPT], pz[TPPT];
    float cw[TPPT][8];
    #pragma unroll
    for (int p = 0; p < TPPT; ++p) {
        int idx = base + p * TBLOCK + tid;
        size_t j = (idx < B) ? (size_t)idx : 0;
        px[p] = x[3*j+0]; py[p] = x[3*j+1]; pz[p] = x[3*j+2];
        float ax = 1.0f - px[p], ay = 1.0f - py[p], az = 1.0f - pz[p];
        cw[p][0] = (ax*ay)*az;       cw[p][1] = (px[p]*ay)*az;
        cw[p][2] = (px[p]*py[p])*az; cw[p][3] = (ax*py[p])*az;
        cw[p][4] = (ax*ay)*pz[p];    cw[p][5] = (px[p]*ay)*pz[p];
        cw[p][6] = (px[p]*py[p])*pz[p]; cw[p][7] = (ax*py[p])*pz[p];
    }

    stage_bf<TBLOCK>(tb, 0, tab[0], tid, wid);

    float o[TPPT][16];

    #pragma unroll
    for (int l = 0; l < NLEV; ++l) {
        if (l + 1 < NLEV) {
            stage_bf<TBLOCK>(tb, l + 1, tab[(l + 1) & 1], tid, wid);
            asm volatile("s_waitcnt vmcnt(8)" ::: "memory");
        } else {
            asm volatile("s_waitcnt vmcnt(0)" ::: "memory");
        }
        asm volatile("s_barrier" ::: "memory");

        const uint32_t* buf = tab[l & 1];
        #pragma unroll
        for (int p = 0; p < TPPT; ++p) {
            float2 a = level_accum_bf(buf, res.r[l], px[p], py[p], pz[p], cw[p]);
            o[p][2*(l & 7) + 0] = a.x;
            o[p][2*(l & 7) + 1] = a.y;
        }

        if ((l & 7) == 7) {
            const int half = l >> 3;
            #pragma unroll
            for (int p = 0; p < TPPT; ++p) {
                int idx = base + p * TBLOCK + tid;
                if (idx < B) {
                    float* po = out + (size_t)idx * (2*NLEV) + half * 16;
                    #pragma unroll
                    for (int q = 0; q < 4; ++q) {
                        float4 v;
                        v.x = o[p][4*q+0]; v.y = o[p][4*q+1];
                        v.z = o[p][4*q+2]; v.w = o[p][4*q+3];
                        ((float4*)po)[q] = v;
                    }
                }
            }
        }

        asm volatile("s_barrier" ::: "memory");
    }
}

// ---- safe no-workspace fallback: direct global gather ----------------------
__global__ __launch_bounds__(256) void mrhe_direct(
    const float* __restrict__ x,
    const float* __restrict__ tables,
    float* __restrict__ out,
    ResArr res, int B)
{
    int i = blockIdx.x * blockDim.x + threadIdx.x;
    if (i >= B) return;
    float px = x[3*(size_t)i+0], py = x[3*(size_t)i+1], pz = x[3*(size_t)i+2];
    float ax = 1.0f - px, ay = 1.0f - py, az = 1.0f - pz;
    float cw[8] = {(ax*ay)*az,(px*ay)*az,(px*py)*az,(ax*py)*az,
                   (ax*ay)*pz,(px*ay)*pz,(px*py)*pz,(ax*py)*pz};
    float o[2*NLEV];
    #pragma unroll
    for (int l = 0; l < NLEV; ++l) {
        C8 c = corner_idx(res.r[l], px, py, pz);
        const float2* tbl = (const float2*)tables + (size_t)l * TABLE_SZ;
        float a0 = 0.f, a1 = 0.f;
        #pragma unroll
        for (int k = 0; k < 8; ++k) {
            float2 f = tbl[c.h[k]];
            a0 += f.x * cw[k]; a1 += f.y * cw[k];
        }
        o[2*l+0] = a0; o[2*l+1] = a1;
    }
    float4* po = (float4*)(out + (size_t)i * (2*NLEV));
    #pragma unroll
    for (int q = 0; q < (2*NLEV)/4; ++q) {
        float4 v; v.x = o[4*q+0]; v.y = o[4*q+1]; v.z = o[4*q+2]; v.w = o[4*q+3];
        po[q] = v;
    }
}

extern "C" void kernel_launch(void* const* d_in, const int* in_sizes, int n_in,
                              void* d_out, int out_size, void* d_ws, size_t ws_size,
                              hipStream_t stream)
{
    const float* x      = (const float*)d_in[0];
    const float* tables = (const float*)d_in[1];
    float* out = (float*)d_out;
    int B = in_sizes[0] / 3;

    // b = exp((log(512)-log(16))/15); res_l = floor(16 * b**l)  (host libm)
    ResArr res;
    float bgrow = expf((logf(512.0f) - logf(16.0f)) / 15.0f);
    for (int l = 0; l < NLEV; ++l)
        res.r[l] = floorf(16.0f * powf(bgrow, (float)l));

    const int n_entries = NLEV * TABLE_SZ;
    const size_t need = (size_t)n_entries * 4;          // 1 MiB packed bf16x2

    if (ws_size >= need && d_ws) {
        uint32_t* tb = (uint32_t*)d_ws;
        hipLaunchKernelGGL(cvt_tables, dim3(n_entries/4/256), dim3(256), 0, stream,
                           tables, tb, n_entries);

        hipFuncAttributes attr{};
        hipError_t e = hipFuncGetAttributes(&attr, (const void*)mrhe_hyb);
        bool useHyb = (e == hipSuccess) && (attr.localSizeBytes == 0);

        if (useHyb) {
            int grid = (B + BLOCK - 1) / BLOCK;
            hipLaunchKernelGGL(mrhe_hyb, dim3(grid), dim3(BLOCK), 0, stream,
                               x, tables, tb, out, res, B);
        } else {
            int per_block = 512 * 2;
            int grid = (B + per_block - 1) / per_block;
            hipLaunchKernelGGL((mrhe_db<512, 2>), dim3(grid), dim3(512), 0, stream,
                               x, tb, out, res, B);
        }
    } else {
        int grid = (B + 255) / 256;
        hipLaunchKernelGGL(mrhe_direct, dim3(grid), dim3(256), 0, stream,
                           x, tables, out, res, B);
    }
}

// Round 15
// 109.181 us; speedup vs baseline: 1.5686x; 1.5686x over previous
//
#include <hip/hip_runtime.h>
#include <cmath>

#define TABLE_SZ 16384
#define NLEV 16

struct ResArr { float r[NLEV]; };

// ---------------- prologue: tables f32 -> packed fp16x2 (RNE) ---------------
// fp16 on ~1e-4 values: abs err <= 6e-8 (better than bf16's 2e-7); f32->f16
// cast uses RNE; f16->f32 on consume is exact (denormals included).
__global__ __launch_bounds__(256) void cvt_tables(
    const float* __restrict__ src, uint32_t* __restrict__ dst, int n_entries)
{
    int i = blockIdx.x * blockDim.x + threadIdx.x;   // 4 entries per thread
    int e = i * 4;
    if (e + 3 < n_entries) {
        const float4* s4 = (const float4*)(src) + i * 2;
        float4 a = s4[0], b = s4[1];
        float v[8] = {a.x,a.y,a.z,a.w,b.x,b.y,b.z,b.w};
        uint32_t o[4];
        #pragma unroll
        for (int k = 0; k < 4; ++k) {
            unsigned short lo = __builtin_bit_cast(unsigned short, (_Float16)v[2*k+0]);
            unsigned short hi = __builtin_bit_cast(unsigned short, (_Float16)v[2*k+1]);
            o[k] = (uint32_t)lo | ((uint32_t)hi << 16);   // lo=feat0, hi=feat1
        }
        *(uint4*)(dst + e) = make_uint4(o[0], o[1], o[2], o[3]);
    }
}

// ---------------- helpers ----------------------------------------------------
template <int TBLOCK>
__device__ __forceinline__ void stage_h(const uint32_t* __restrict__ tb, int l,
                                        uint32_t* buf, int tid, int wid)
{
    const char* gbase = (const char*)tb + (size_t)l * (TABLE_SZ * 4);
    #pragma unroll
    for (int j = 0; j < (TABLE_SZ * 4) / (TBLOCK * 16); ++j) {
        uint32_t goff = (uint32_t)(j * (TBLOCK * 16) + tid * 16);   // per-lane
        uint32_t loff = (uint32_t)(j * (TBLOCK * 16) + wid * 1024); // wave-uniform
        __builtin_amdgcn_global_load_lds(
            (const __attribute__((address_space(1))) uint32_t*)(gbase + goff),
            (__attribute__((address_space(3))) uint32_t*)((char*)buf + loff),
            16, 0, 0);
    }
}

// x in [0,1): interp weight w = x - floor(x) == x exactly, so coords double as
// trilinear weights (faithful). cw precomputed per point: product order
// (x*y)*z, corners v0..v7, k-ascending accumulation.
// high = ceil (NOT low+1); low = trunc (sp in [0,512) >= 0).
// Strength reduction: P*hy = P*ly + (hy!=ly ? P : 0)  (full-rate cmp/cndmask/
// add replaces a quarter-rate v_mul_lo_u32).
__device__ __forceinline__ float2 level_accum_h(const uint32_t* tab, float r,
                                                float px, float py, float pz,
                                                const float* cw)
{
    const uint32_t P1 = 2654435761u, P2 = 805459861u;
    const uint32_t m  = TABLE_SZ - 1u;

    float sx = r*px, sy = r*py, sz = r*pz;
    uint32_t lx = (uint32_t)sx,  hx = (uint32_t)ceilf(sx);
    uint32_t ly = (uint32_t)sy,  hy = (uint32_t)ceilf(sy);
    uint32_t lz = (uint32_t)sz,  hz = (uint32_t)ceilf(sz);
    uint32_t yl = P1*ly;
    uint32_t yh = (hy == ly) ? yl : yl + P1;
    uint32_t zl = P2*lz;
    uint32_t zh = (hz == lz) ? zl : zl + P2;

    uint32_t h0 = (lx ^ yl ^ zl) & m;
    uint32_t h1 = (hx ^ yl ^ zl) & m;
    uint32_t h2 = (hx ^ yh ^ zl) & m;
    uint32_t h3 = (lx ^ yh ^ zl) & m;
    uint32_t h4 = (lx ^ yl ^ zh) & m;
    uint32_t h5 = (hx ^ yl ^ zh) & m;
    uint32_t h6 = (hx ^ yh ^ zh) & m;
    uint32_t h7 = (lx ^ yh ^ zh) & m;

    uint32_t v0 = tab[h0], v1 = tab[h1], v2 = tab[h2], v3 = tab[h3];
    uint32_t v4 = tab[h4], v5 = tab[h5], v6 = tab[h6], v7 = tab[h7];

    float a0 = 0.f, a1 = 0.f;
    uint32_t vv[8] = {v0,v1,v2,v3,v4,v5,v6,v7};
    #pragma unroll
    for (int k = 0; k < 8; ++k) {
        _Float16 lo = __builtin_bit_cast(_Float16, (unsigned short)(vv[k] & 0xFFFFu));
        _Float16 hi = __builtin_bit_cast(_Float16, (unsigned short)(vv[k] >> 16));
        a0 += (float)lo * cw[k];    // -> v_fma_mix_f32 (f16 src folded)
        a1 += (float)hi * cw[k];
    }
    return make_float2(a0, a1);
}

// -------- main kernel: double-buffered fp16 staging, counted vmcnt ----------
// Per level l: issue DMA for l+1 into buf^1; s_waitcnt vmcnt(R) (level-l's R
// loads are the OLDER entries; vmem retires in order); raw s_barrier; gather
// level l overlapping l+1's DMA; end barrier protects buf reuse. NEVER
// __syncthreads() in the loop (drains vmcnt to 0).
template <int TBLOCK, int TPPT>
__global__ __launch_bounds__(TBLOCK) void mrhe_db(
    const float* __restrict__ x,
    const uint32_t* __restrict__ tb,
    float* __restrict__ out,
    ResArr res, int B)
{
    constexpr int ROUNDS = (TABLE_SZ * 4) / (TBLOCK * 16);
    static_assert(ROUNDS == 8 || ROUNDS == 16, "vmcnt literal must match");

    __shared__ uint32_t tab[2][TABLE_SZ];   // 2 x 64 KiB

    const int tid  = threadIdx.x;
    const int wid  = tid >> 6;
    const int base = blockIdx.x * (TBLOCK * TPPT);

    float px[TPPT], py[TPPT], pz[TPPT];
    float cw[TPPT][8];                 // level-invariant corner weights
    #pragma unroll
    for (int p = 0; p < TPPT; ++p) {
        int idx = base + p * TBLOCK + tid;
        size_t j = (idx < B) ? (size_t)idx : 0;
        px[p] = x[3*j+0]; py[p] = x[3*j+1]; pz[p] = x[3*j+2];
        float ax = 1.0f - px[p], ay = 1.0f - py[p], az = 1.0f - pz[p];
        cw[p][0] = (ax*ay)*az;          cw[p][1] = (px[p]*ay)*az;
        cw[p][2] = (px[p]*py[p])*az;    cw[p][3] = (ax*py[p])*az;
        cw[p][4] = (ax*ay)*pz[p];       cw[p][5] = (px[p]*ay)*pz[p];
        cw[p][6] = (px[p]*py[p])*pz[p]; cw[p][7] = (ax*py[p])*pz[p];
    }

    stage_h<TBLOCK>(tb, 0, tab[0], tid, wid);   // prologue: level 0 -> buf 0

    float o[TPPT][16];   // current 64B window — statically indexed only

    #pragma unroll
    for (int l = 0; l < NLEV; ++l) {
        if (l + 1 < NLEV) {
            stage_h<TBLOCK>(tb, l + 1, tab[(l + 1) & 1], tid, wid);
            if constexpr (ROUNDS == 8)
                asm volatile("s_waitcnt vmcnt(8)" ::: "memory");
            else
                asm volatile("s_waitcnt vmcnt(16)" ::: "memory");
        } else {
            asm volatile("s_waitcnt vmcnt(0)" ::: "memory");
        }
        asm volatile("s_barrier" ::: "memory");   // level-l DMA visible to all

        const uint32_t* buf = tab[l & 1];
        #pragma unroll
        for (int p = 0; p < TPPT; ++p) {
            float2 a = level_accum_h(buf, res.r[l], px[p], py[p], pz[p], cw[p]);
            o[p][2*(l & 7) + 0] = a.x;
            o[p][2*(l & 7) + 1] = a.y;
        }

        if ((l & 7) == 7) {
            // 64 contiguous 64B-aligned bytes per point (full sectors, no RMW)
            const int half = l >> 3;
            #pragma unroll
            for (int p = 0; p < TPPT; ++p) {
                int idx = base + p * TBLOCK + tid;
                if (idx < B) {
                    float* po = out + (size_t)idx * (2*NLEV) + half * 16;
                    #pragma unroll
                    for (int q = 0; q < 4; ++q) {
                        float4 v;
                        v.x = o[p][4*q+0]; v.y = o[p][4*q+1];
                        v.z = o[p][4*q+2]; v.w = o[p][4*q+3];
                        ((float4*)po)[q] = v;
                    }
                }
            }
        }

        asm volatile("s_barrier" ::: "memory");   // protect buf before reuse
    }
}

// ---- safe no-workspace fallback: direct global gather ----------------------
__global__ __launch_bounds__(256) void mrhe_direct(
    const float* __restrict__ x,
    const float* __restrict__ tables,
    float* __restrict__ out,
    ResArr res, int B)
{
    int i = blockIdx.x * blockDim.x + threadIdx.x;
    if (i >= B) return;
    float px = x[3*(size_t)i+0], py = x[3*(size_t)i+1], pz = x[3*(size_t)i+2];
    float ax = 1.0f - px, ay = 1.0f - py, az = 1.0f - pz;
    float cw[8] = {(ax*ay)*az,(px*ay)*az,(px*py)*az,(ax*py)*az,
                   (ax*ay)*pz,(px*ay)*pz,(px*py)*pz,(ax*py)*pz};
    const uint32_t P1 = 2654435761u, P2 = 805459861u, m = TABLE_SZ - 1u;
    float o[2*NLEV];
    #pragma unroll
    for (int l = 0; l < NLEV; ++l) {
        float r = res.r[l];
        float sx = r*px, sy = r*py, sz = r*pz;
        uint32_t lx = (uint32_t)sx, hx = (uint32_t)ceilf(sx);
        uint32_t ly = (uint32_t)sy, hy = (uint32_t)ceilf(sy);
        uint32_t lz = (uint32_t)sz, hz = (uint32_t)ceilf(sz);
        uint32_t yl = P1*ly, yh = P1*hy, zl = P2*lz, zh = P2*hz;
        uint32_t h[8] = {(lx^yl^zl)&m,(hx^yl^zl)&m,(hx^yh^zl)&m,(lx^yh^zl)&m,
                         (lx^yl^zh)&m,(hx^yl^zh)&m,(hx^yh^zh)&m,(lx^yh^zh)&m};
        const float2* tbl = (const float2*)tables + (size_t)l * TABLE_SZ;
        float a0 = 0.f, a1 = 0.f;
        #pragma unroll
        for (int k = 0; k < 8; ++k) {
            float2 f = tbl[h[k]];
            a0 += f.x * cw[k]; a1 += f.y * cw[k];
        }
        o[2*l+0] = a0; o[2*l+1] = a1;
    }
    float4* po = (float4*)(out + (size_t)i * (2*NLEV));
    #pragma unroll
    for (int q = 0; q < (2*NLEV)/4; ++q) {
        float4 v; v.x = o[4*q+0]; v.y = o[4*q+1]; v.z = o[4*q+2]; v.w = o[4*q+3];
        po[q] = v;
    }
}

extern "C" void kernel_launch(void* const* d_in, const int* in_sizes, int n_in,
                              void* d_out, int out_size, void* d_ws, size_t ws_size,
                              hipStream_t stream)
{
    const float* x      = (const float*)d_in[0];
    const float* tables = (const float*)d_in[1];
    float* out = (float*)d_out;
    int B = in_sizes[0] / 3;

    // b = exp((log(512)-log(16))/15); res_l = floor(16 * b**l)  (host libm)
    ResArr res;
    float bgrow = expf((logf(512.0f) - logf(16.0f)) / 15.0f);
    for (int l = 0; l < NLEV; ++l)
        res.r[l] = floorf(16.0f * powf(bgrow, (float)l));

    const int n_entries = NLEV * TABLE_SZ;
    const size_t need = (size_t)n_entries * 4;          // 1 MiB packed fp16x2

    if (ws_size >= need && d_ws) {
        uint32_t* tb = (uint32_t*)d_ws;
        hipLaunchKernelGGL(cvt_tables, dim3(n_entries/4/256), dim3(256), 0, stream,
                           tables, tb, n_entries);

        // Preferred: proven r12 shape (512-thr, PPT=2, 116 VGPR). Spill guard
        // (capture-safe host query) falls back to 256-thr/PPT=4.
        hipFuncAttributes attr{};
        hipError_t e = hipFuncGetAttributes(&attr, (const void*)mrhe_db<512, 2>);
        bool use512 = (e == hipSuccess) && (attr.localSizeBytes == 0);

        if (use512) {
            int per_block = 512 * 2;
            int grid = (B + per_block - 1) / per_block;
            hipLaunchKernelGGL((mrhe_db<512, 2>), dim3(grid), dim3(512), 0, stream,
                               x, tb, out, res, B);
        } else {
            int per_block = 256 * 4;
            int grid = (B + per_block - 1) / per_block;
            hipLaunchKernelGGL((mrhe_db<256, 4>), dim3(grid), dim3(256), 0, stream,
                               x, tb, out, res, B);
        }
    } else {
        int grid = (B + 255) / 256;
        hipLaunchKernelGGL(mrhe_direct, dim3(grid), dim3(256), 0, stream,
                           x, tables, out, res, B);
    }
}